// Round 1
// baseline (5069.423 us; speedup 1.0000x reference)
//
#include <hip/hip_runtime.h>

#define NNODES 50000
#define NEDGES 200000
#define DD 128
#define LN_EPS 1e-5f

#define BM 64      // rows per block tile
#define TM 4       // rows per thread
#define TN 8       // cols per thread
#define NTH 256
#define KC 32      // K chunk
#define XS_STRIDE 36   // 144B rows: 16B aligned, bank offset 4/row
#define HB_STRIDE 132  // 528B rows: 16B aligned, bank offset 4/row

template<int MODE>  // 0 = edge MLP, 1 = node MLP
__global__ __launch_bounds__(NTH, 2)
void mgn_mlp(const float* __restrict__ nodef,
             const float* __restrict__ edgef,
             const int* __restrict__ senders,
             const int* __restrict__ receivers,
             const float* __restrict__ W1, const float* __restrict__ b1,
             const float* __restrict__ W2, const float* __restrict__ b2,
             const float* __restrict__ W3, const float* __restrict__ b3,
             const float* __restrict__ gamma, const float* __restrict__ beta,
             float* __restrict__ agg,
             float* __restrict__ outp)
{
    __shared__ float Xs[BM * XS_STRIDE];
    __shared__ float Ws[KC * DD];
    __shared__ float Hb[BM * HB_STRIDE];
    __shared__ int sidx[BM];
    __shared__ int ridx[BM];

    const int t = threadIdx.x;
    const int row0 = blockIdx.x * BM;
    constexpr int NROWS = (MODE == 0) ? NEDGES : NNODES;
    constexpr int NCH1  = (MODE == 0) ? 12 : 8;   // K = 384 or 256

    if (MODE == 0) {
        if (t < BM) {
            int e = row0 + t;
            sidx[t] = (e < NROWS) ? senders[e]   : 0;
            ridx[t] = (e < NROWS) ? receivers[e] : 0;
        }
    }
    __syncthreads();

    const int rg = t >> 4;       // 0..15
    const int cg = t & 15;       // 0..15
    const int r0 = rg * TM;      // local row base
    const int c0 = cg * TN;      // col base

    float acc[TM][TN];
    #pragma unroll
    for (int i = 0; i < TM; ++i)
        #pragma unroll
        for (int j = 0; j < TN; ++j) acc[i][j] = 0.f;

    float4 xpre[2];
    float4 wpre[4];

    // ---- prefetch helpers (global -> regs), store helpers (regs -> LDS) ----
    auto loadX = [&](int ch) {
        #pragma unroll
        for (int i = 0; i < 2; ++i) {
            int idx = t + i * NTH;          // 512 float4 = 64 rows x 8 quads
            int lrow = idx >> 3, q = idx & 7;
            int e = row0 + lrow;
            const float* p = nullptr;
            if (MODE == 0) {
                if (e < NROWS) {
                    if (ch < 4)      p = nodef + (size_t)sidx[lrow] * DD + ch * KC;
                    else if (ch < 8) p = nodef + (size_t)ridx[lrow] * DD + (ch - 4) * KC;
                    else             p = edgef + (size_t)e * DD + (ch - 8) * KC;
                }
            } else {
                if (e < NROWS) {
                    if (ch < 4) p = nodef + (size_t)e * DD + ch * KC;
                    else        p = agg   + (size_t)e * DD + (ch - 4) * KC;
                }
            }
            xpre[i] = p ? *(const float4*)(p + q * 4) : make_float4(0.f, 0.f, 0.f, 0.f);
        }
    };
    auto storeX = [&]() {
        #pragma unroll
        for (int i = 0; i < 2; ++i) {
            int idx = t + i * NTH;
            int lrow = idx >> 3, q = idx & 7;
            *(float4*)&Xs[lrow * XS_STRIDE + q * 4] = xpre[i];
        }
    };
    auto loadW = [&](const float* W, int ch) {
        #pragma unroll
        for (int i = 0; i < 4; ++i) {
            int idx = t + i * NTH;          // 1024 float4 = 32 rows x 32 quads
            int wrow = idx >> 5, wq = idx & 31;
            wpre[i] = *(const float4*)(W + (size_t)(ch * KC + wrow) * DD + wq * 4);
        }
    };
    auto storeW = [&]() {
        #pragma unroll
        for (int i = 0; i < 4; ++i) {
            int idx = t + i * NTH;
            int wrow = idx >> 5, wq = idx & 31;
            *(float4*)&Ws[wrow * DD + wq * 4] = wpre[i];
        }
    };

    // ---- inner GEMM on one K-chunk: acc += X[.,kchunk] * Wchunk ----
    auto gemm_chunk = [&](const float* xb, int xstride) {
        #pragma unroll
        for (int kk4 = 0; kk4 < KC / 4; ++kk4) {
            float4 xv[TM];
            #pragma unroll
            for (int i = 0; i < TM; ++i)
                xv[i] = *(const float4*)&xb[(r0 + i) * xstride + kk4 * 4];
            #pragma unroll
            for (int q = 0; q < 4; ++q) {
                const int kk = kk4 * 4 + q;
                const float4 w0 = *(const float4*)&Ws[kk * DD + c0];
                const float4 w1 = *(const float4*)&Ws[kk * DD + c0 + 4];
                #pragma unroll
                for (int i = 0; i < TM; ++i) {
                    const float x = (q == 0) ? xv[i].x : (q == 1) ? xv[i].y
                                  : (q == 2) ? xv[i].z : xv[i].w;
                    acc[i][0] = fmaf(x, w0.x, acc[i][0]);
                    acc[i][1] = fmaf(x, w0.y, acc[i][1]);
                    acc[i][2] = fmaf(x, w0.z, acc[i][2]);
                    acc[i][3] = fmaf(x, w0.w, acc[i][3]);
                    acc[i][4] = fmaf(x, w1.x, acc[i][4]);
                    acc[i][5] = fmaf(x, w1.y, acc[i][5]);
                    acc[i][6] = fmaf(x, w1.z, acc[i][6]);
                    acc[i][7] = fmaf(x, w1.w, acc[i][7]);
                }
            }
        }
    };

    // ---- bias + relu -> Hb, reset acc ----
    auto bias_relu_store = [&](const float* b) {
        float4 bv0 = *(const float4*)&b[c0];
        float4 bv1 = *(const float4*)&b[c0 + 4];
        float bb[8] = {bv0.x, bv0.y, bv0.z, bv0.w, bv1.x, bv1.y, bv1.z, bv1.w};
        #pragma unroll
        for (int i = 0; i < TM; ++i)
            #pragma unroll
            for (int j = 0; j < TN; ++j) {
                float h = fmaxf(acc[i][j] + bb[j], 0.f);
                Hb[(r0 + i) * HB_STRIDE + c0 + j] = h;
                acc[i][j] = 0.f;
            }
    };

    // ================= phase 1: X (gathered) @ W1 =================
    loadX(0); loadW(W1, 0);
    storeX(); storeW();
    __syncthreads();
    for (int ch = 0; ch < NCH1; ++ch) {
        bool more = (ch + 1 < NCH1);
        if (more) { loadX(ch + 1); loadW(W1, ch + 1); }
        gemm_chunk(Xs, XS_STRIDE);
        __syncthreads();
        if (more) { storeX(); storeW(); __syncthreads(); }
    }
    bias_relu_store(b1);

    // ================= phase 2: H1 @ W2 =================
    auto gemm_from_Hb = [&](const float* W) {
        loadW(W, 0); storeW();
        __syncthreads();
        for (int ch = 0; ch < 4; ++ch) {
            bool more = (ch < 3);
            if (more) loadW(W, ch + 1);
            gemm_chunk(&Hb[ch * KC], HB_STRIDE);
            __syncthreads();
            if (more) { storeW(); __syncthreads(); }
        }
    };
    gemm_from_Hb(W2);
    bias_relu_store(b2);

    // ================= phase 3: H2 @ W3 =================
    gemm_from_Hb(W3);

    // add b3 (no relu)
    {
        float4 bv0 = *(const float4*)&b3[c0];
        float4 bv1 = *(const float4*)&b3[c0 + 4];
        float bb[8] = {bv0.x, bv0.y, bv0.z, bv0.w, bv1.x, bv1.y, bv1.z, bv1.w};
        #pragma unroll
        for (int i = 0; i < TM; ++i)
            #pragma unroll
            for (int j = 0; j < TN; ++j) acc[i][j] += bb[j];
    }

    // ================= LayerNorm + residual + (edge: scatter) =================
    float4 g0 = *(const float4*)&gamma[c0];
    float4 g1 = *(const float4*)&gamma[c0 + 4];
    float4 be0 = *(const float4*)&beta[c0];
    float4 be1 = *(const float4*)&beta[c0 + 4];
    float gb[8] = {g0.x, g0.y, g0.z, g0.w, g1.x, g1.y, g1.z, g1.w};
    float bb[8] = {be0.x, be0.y, be0.z, be0.w, be1.x, be1.y, be1.z, be1.w};

    #pragma unroll
    for (int i = 0; i < TM; ++i) {
        float s = 0.f, s2 = 0.f;
        #pragma unroll
        for (int j = 0; j < TN; ++j) { float v = acc[i][j]; s += v; s2 += v * v; }
        // reduce across the 16 lanes (same row set) of this lane-group
        #pragma unroll
        for (int m = 1; m < 16; m <<= 1) {
            s  += __shfl_xor(s,  m);
            s2 += __shfl_xor(s2, m);
        }
        const float mu  = s * (1.f / DD);
        const float var = s2 * (1.f / DD) - mu * mu;
        const float rs  = rsqrtf(var + LN_EPS);

        const int e = row0 + r0 + i;
        if (e < NROWS) {
            float y[8];
            #pragma unroll
            for (int j = 0; j < TN; ++j)
                y[j] = (acc[i][j] - mu) * rs * gb[j] + bb[j];

            if (MODE == 0) {
                const float4 e0 = *(const float4*)&edgef[(size_t)e * DD + c0];
                const float4 e1 = *(const float4*)&edgef[(size_t)e * DD + c0 + 4];
                float4 o0 = make_float4(y[0] + e0.x, y[1] + e0.y, y[2] + e0.z, y[3] + e0.w);
                float4 o1 = make_float4(y[4] + e1.x, y[5] + e1.y, y[6] + e1.z, y[7] + e1.w);
                *(float4*)&outp[(size_t)e * DD + c0]     = o0;
                *(float4*)&outp[(size_t)e * DD + c0 + 4] = o1;
                float* ap = agg + (size_t)ridx[r0 + i] * DD + c0;
                #pragma unroll
                for (int j = 0; j < TN; ++j) atomicAdd(ap + j, y[j]);
            } else {
                const float4 n0 = *(const float4*)&nodef[(size_t)e * DD + c0];
                const float4 n1 = *(const float4*)&nodef[(size_t)e * DD + c0 + 4];
                float4 o0 = make_float4(y[0] + n0.x, y[1] + n0.y, y[2] + n0.z, y[3] + n0.w);
                float4 o1 = make_float4(y[4] + n1.x, y[5] + n1.y, y[6] + n1.z, y[7] + n1.w);
                *(float4*)&outp[(size_t)e * DD + c0]     = o0;
                *(float4*)&outp[(size_t)e * DD + c0 + 4] = o1;
            }
        }
    }
}

extern "C" void kernel_launch(void* const* d_in, const int* in_sizes, int n_in,
                              void* d_out, int out_size, void* d_ws, size_t ws_size,
                              hipStream_t stream) {
    const float* nodef = (const float*)d_in[0];
    const float* edgef = (const float*)d_in[1];
    const int* senders   = (const int*)d_in[2];
    const int* receivers = (const int*)d_in[3];
    const float* We1 = (const float*)d_in[4],  *be1 = (const float*)d_in[5];
    const float* We2 = (const float*)d_in[6],  *be2 = (const float*)d_in[7];
    const float* We3 = (const float*)d_in[8],  *be3 = (const float*)d_in[9];
    const float* ge  = (const float*)d_in[10], *bege = (const float*)d_in[11];
    const float* Wn1 = (const float*)d_in[12], *bn1 = (const float*)d_in[13];
    const float* Wn2 = (const float*)d_in[14], *bn2 = (const float*)d_in[15];
    const float* Wn3 = (const float*)d_in[16], *bn3 = (const float*)d_in[17];
    const float* gn  = (const float*)d_in[18], *begn = (const float*)d_in[19];

    float* out_node = (float*)d_out;                        // [NNODES*DD]
    float* out_edge = (float*)d_out + (size_t)NNODES * DD;  // [NEDGES*DD]
    float* agg = (float*)d_ws;                              // [NNODES*DD] scratch

    hipMemsetAsync(agg, 0, (size_t)NNODES * DD * sizeof(float), stream);

    dim3 blk(NTH);
    mgn_mlp<0><<<dim3((NEDGES + BM - 1) / BM), blk, 0, stream>>>(
        nodef, edgef, senders, receivers,
        We1, be1, We2, be2, We3, be3, ge, bege, agg, out_edge);
    mgn_mlp<1><<<dim3((NNODES + BM - 1) / BM), blk, 0, stream>>>(
        nodef, edgef, senders, receivers,
        Wn1, bn1, Wn2, bn2, Wn3, bn3, gn, begn, agg, out_node);
}

// Round 2
// 441.103 us; speedup vs baseline: 11.4926x; 11.4926x over previous
//
#include <hip/hip_runtime.h>

#define NNODES 50000
#define NEDGES 200000
#define DD 128
#define LN_EPS 1e-5f
#define NTH 256

typedef __attribute__((ext_vector_type(8))) short bf16x8;
typedef __attribute__((ext_vector_type(4))) float f32x4;

__device__ __forceinline__ unsigned short bf_rne(float f) {
    union { float f; unsigned u; } v; v.f = f;
    return (unsigned short)((v.u + 0x7fffu + ((v.u >> 16) & 1u)) >> 16);
}

// ---------------------------------------------------------------------------
// Weight image builder: W [K][128] fp32  ->  bf16 "LDS image" per 64-k chunk:
//   byte offset = c*16384 + n*128 + ((s*16) ^ ((n&7)<<4)),  content
//   Wt[n][c*64 + s*8 + e]  (e = 0..7 within the 16B slot)
// ---------------------------------------------------------------------------
__global__ void build_wimg(const float* __restrict__ We1, const float* __restrict__ We2,
                           const float* __restrict__ We3, const float* __restrict__ Wn1,
                           const float* __restrict__ Wn2, const float* __restrict__ Wn3,
                           char* __restrict__ img_e, char* __restrict__ img_n) {
    int tid = blockIdx.x * NTH + threadIdx.x;
    const float* W; char* dst; int q;
    if      (tid <  6144) { W = We1; dst = img_e;             q = tid;         }
    else if (tid <  8192) { W = We2; dst = img_e + 6 * 16384; q = tid - 6144;  }
    else if (tid < 10240) { W = We3; dst = img_e + 8 * 16384; q = tid - 8192;  }
    else if (tid < 14336) { W = Wn1; dst = img_n;             q = tid - 10240; }
    else if (tid < 16384) { W = Wn2; dst = img_n + 4 * 16384; q = tid - 14336; }
    else if (tid < 18432) { W = Wn3; dst = img_n + 6 * 16384; q = tid - 16384; }
    else return;
    int c = q >> 10, rem = q & 1023, n = rem >> 3, s = rem & 7;
    unsigned short o[8];
    #pragma unroll
    for (int e = 0; e < 8; ++e)
        o[e] = bf_rne(W[(size_t)(c * 64 + s * 8 + e) * DD + n]);
    uint4 val;
    val.x = (unsigned)o[0] | ((unsigned)o[1] << 16);
    val.y = (unsigned)o[2] | ((unsigned)o[3] << 16);
    val.z = (unsigned)o[4] | ((unsigned)o[5] << 16);
    val.w = (unsigned)o[6] | ((unsigned)o[7] << 16);
    *(uint4*)(dst + (size_t)c * 16384 + n * 128 + ((unsigned)(s * 16) ^ ((unsigned)(n & 7) << 4))) = val;
}

// ---------------------------------------------------------------------------
// Fused MLP kernel.  MODE 0 = edge (K=384, gather, scatter-atomics),
//                    MODE 1 = node (K=256, direct rows).
// Per block: 64 rows x 128 cols.  Wave w owns rows w*16..w*16+15, all cols.
// MFMA 16x16x32 bf16: A = Wt[n][k] fragment, B = X[m][k] fragment.
//   A/B lane map: outer = l&15, k = (l>>4)*8 + e.
//   D   lane map: n = nt*16 + (l>>4)*4 + r, m = l&15.    (m89-verified)
// No __syncthreads anywhere: Hb rows are wave-private.
// ---------------------------------------------------------------------------
template<int MODE>
__global__ __launch_bounds__(NTH, 3)
void mgn_mfma(const float* __restrict__ nodef, const float* __restrict__ edgef,
              const int* __restrict__ senders, const int* __restrict__ receivers,
              const char* __restrict__ img,
              const float* __restrict__ b1, const float* __restrict__ b2,
              const float* __restrict__ b3,
              const float* __restrict__ gamma, const float* __restrict__ beta,
              float* __restrict__ agg, float* __restrict__ outp)
{
    __shared__ char Hb[16384];   // H1/H2: 2 halves x [64 rows][64 k] bf16, swizzled

    const int t  = threadIdx.x;
    const int w  = t >> 6;
    const int l  = t & 63;
    const int lr = l & 15;           // outer index within 16-tile
    const int g  = l >> 4;           // k-group 0..3
    const int m_local = w * 16 + lr;
    const int row0 = blockIdx.x * 64;
    const int gm = row0 + m_local;
    constexpr int NROWS = (MODE == 0) ? NEDGES : NNODES;
    constexpr int NK1   = (MODE == 0) ? 12 : 8;   // K/32 for layer 1
    const int gmc = gm < NROWS ? gm : NROWS - 1;
    const unsigned swz = (unsigned)(lr & 7) << 4;

    int srow = 0, rrow = 0;
    if (MODE == 0) { srow = senders[gmc]; rrow = receivers[gmc]; }

    f32x4 acc[8];
    const f32x4 fzero = {0.f, 0.f, 0.f, 0.f};
    #pragma unroll
    for (int nt = 0; nt < 8; ++nt) acc[nt] = fzero;

    // ---- A-fragment loader: 8 ntiles from the weight image (bf16, pre-swizzled)
    auto loadA = [&](bf16x8* a, const char* imgph, int ks) {
        const char* base = imgph + (size_t)(ks >> 1) * 16384
                         + ((unsigned)((ks & 1) * 64 + g * 16) ^ swz);
        #pragma unroll
        for (int nt = 0; nt < 8; ++nt)
            a[nt] = *(const bf16x8*)(base + (nt * 16 + lr) * 128);
    };

    // ---- B-fragment raw loader (fp32 x8 from global rows)
    auto loadB1 = [&](f32x4* b, int ks) {
        const float* base;
        if (MODE == 0) {
            int seg = ks >> 2;
            base = (seg == 0) ? nodef + (size_t)srow * DD
                 : (seg == 1) ? nodef + (size_t)rrow * DD
                              : edgef + (size_t)gmc * DD;
        } else {
            base = (ks < 4) ? nodef + (size_t)gmc * DD
                            : agg   + (size_t)gmc * DD;
        }
        const float* src = base + (ks & 3) * 32 + g * 8;
        b[0] = *(const f32x4*)src;
        b[1] = *(const f32x4*)(src + 4);
    };

    auto cvtB = [&](const f32x4* braw) {
        bf16x8 r;
        #pragma unroll
        for (int i = 0; i < 4; ++i) r[i]     = (short)bf_rne(braw[0][i]);
        #pragma unroll
        for (int i = 0; i < 4; ++i) r[4 + i] = (short)bf_rne(braw[1][i]);
        return r;
    };

    // ---- H (LDS) B-fragment read, swizzled, wave-private rows
    auto loadBH = [&](int ks) {
        const char* p = &Hb[(ks >> 1) * 8192] + m_local * 128
                      + ((unsigned)((ks & 1) * 64 + g * 16) ^ swz);
        return *(const bf16x8*)p;
    };

    auto domfma = [&](bf16x8* a, bf16x8 b) {
        #pragma unroll
        for (int nt = 0; nt < 8; ++nt)
            acc[nt] = __builtin_amdgcn_mfma_f32_16x16x32_bf16(a[nt], b, acc[nt], 0, 0, 0);
    };

    // ---- bias + relu -> Hb (bf16, swizzled), reset acc
    auto epiH = [&](const float* bias) {
        #pragma unroll
        for (int nt = 0; nt < 8; ++nt) {
            f32x4 bv = *(const f32x4*)(bias + nt * 16 + g * 4);
            unsigned short h[4];
            #pragma unroll
            for (int r = 0; r < 4; ++r)
                h[r] = bf_rne(fmaxf(acc[nt][r] + bv[r], 0.f));
            char* p = &Hb[(nt >> 2) * 8192] + m_local * 128
                    + ((unsigned)(((nt & 3) * 2 + (g >> 1)) * 16) ^ swz) + (g & 1) * 8;
            unsigned lo = (unsigned)h[0] | ((unsigned)h[1] << 16);
            unsigned hi = (unsigned)h[2] | ((unsigned)h[3] << 16);
            *(unsigned long long*)p = (unsigned long long)lo | ((unsigned long long)hi << 32);
            acc[nt] = fzero;
        }
    };

    bf16x8 aA[8], aB[8];
    f32x4  bA[2], bB[2];

    // ================= phase 1: X @ W1 =================
    loadA(aA, img, 0); loadB1(bA, 0);
    #pragma unroll
    for (int ks = 0; ks < NK1; ks += 2) {
        loadA(aB, img, ks + 1); loadB1(bB, ks + 1);
        domfma(aA, cvtB(bA));
        if (ks + 2 < NK1) { loadA(aA, img, ks + 2); loadB1(bA, ks + 2); }
        domfma(aB, cvtB(bB));
    }
    epiH(b1);

    // ================= phase 2: H1 @ W2 =================
    const char* img2 = img + (size_t)((MODE == 0) ? 6 : 4) * 16384;
    loadA(aA, img2, 0);
    #pragma unroll
    for (int ks = 0; ks < 4; ks += 2) {
        loadA(aB, img2, ks + 1);
        domfma(aA, loadBH(ks));
        if (ks + 2 < 4) loadA(aA, img2, ks + 2);
        domfma(aB, loadBH(ks + 1));
    }
    epiH(b2);

    // ================= phase 3: H2 @ W3 =================
    const char* img3 = img2 + 2 * 16384;
    loadA(aA, img3, 0);
    #pragma unroll
    for (int ks = 0; ks < 4; ks += 2) {
        loadA(aB, img3, ks + 1);
        domfma(aA, loadBH(ks));
        if (ks + 2 < 4) loadA(aA, img3, ks + 2);
        domfma(aB, loadBH(ks + 1));
    }

    // ================= bias3 + LayerNorm + residual + scatter =================
    float vsum = 0.f, vsq = 0.f;
    #pragma unroll
    for (int nt = 0; nt < 8; ++nt) {
        f32x4 bv = *(const f32x4*)(b3 + nt * 16 + g * 4);
        #pragma unroll
        for (int r = 0; r < 4; ++r) {
            float v = acc[nt][r] + bv[r];
            acc[nt][r] = v;
            vsum += v; vsq += v * v;
        }
    }
    vsum += __shfl_xor(vsum, 16); vsum += __shfl_xor(vsum, 32);
    vsq  += __shfl_xor(vsq, 16);  vsq  += __shfl_xor(vsq, 32);
    const float mu = vsum * (1.f / DD);
    const float rs = rsqrtf(vsq * (1.f / DD) - mu * mu + LN_EPS);

    if (gm < NROWS) {
        const float* resid = ((MODE == 0) ? edgef : nodef) + (size_t)gm * DD;
        #pragma unroll
        for (int nt = 0; nt < 8; ++nt) {
            const int n0 = nt * 16 + g * 4;
            f32x4 gv = *(const f32x4*)(gamma + n0);
            f32x4 bv = *(const f32x4*)(beta + n0);
            f32x4 rv = *(const f32x4*)(resid + n0);
            f32x4 y, o;
            #pragma unroll
            for (int r = 0; r < 4; ++r) {
                y[r] = (acc[nt][r] - mu) * rs * gv[r] + bv[r];
                o[r] = y[r] + rv[r];
            }
            *(f32x4*)(outp + (size_t)gm * DD + n0) = o;
            if (MODE == 0) {
                float* ap = agg + (size_t)rrow * DD + n0;
                #pragma unroll
                for (int r = 0; r < 4; ++r) atomicAdd(ap + r, y[r]);
            }
        }
    }
}

extern "C" void kernel_launch(void* const* d_in, const int* in_sizes, int n_in,
                              void* d_out, int out_size, void* d_ws, size_t ws_size,
                              hipStream_t stream) {
    const float* nodef = (const float*)d_in[0];
    const float* edgef = (const float*)d_in[1];
    const int* senders   = (const int*)d_in[2];
    const int* receivers = (const int*)d_in[3];
    const float* We1 = (const float*)d_in[4],  *be1 = (const float*)d_in[5];
    const float* We2 = (const float*)d_in[6],  *be2 = (const float*)d_in[7];
    const float* We3 = (const float*)d_in[8],  *be3 = (const float*)d_in[9];
    const float* ge  = (const float*)d_in[10], *bege = (const float*)d_in[11];
    const float* Wn1 = (const float*)d_in[12], *bn1 = (const float*)d_in[13];
    const float* Wn2 = (const float*)d_in[14], *bn2 = (const float*)d_in[15];
    const float* Wn3 = (const float*)d_in[16], *bn3 = (const float*)d_in[17];
    const float* gn  = (const float*)d_in[18], *begn = (const float*)d_in[19];

    float* out_node = (float*)d_out;
    float* out_edge = (float*)d_out + (size_t)NNODES * DD;

    float* agg  = (float*)d_ws;                              // 25.6 MB fp32
    char* img_e = (char*)d_ws + (size_t)NNODES * DD * 4;     // 160 KB
    char* img_n = img_e + 10 * 16384;                        // 128 KB

    hipMemsetAsync(agg, 0, (size_t)NNODES * DD * sizeof(float), stream);
    build_wimg<<<72, NTH, 0, stream>>>(We1, We2, We3, Wn1, Wn2, Wn3, img_e, img_n);

    mgn_mfma<0><<<dim3((NEDGES + 63) / 64), dim3(NTH), 0, stream>>>(
        nodef, edgef, senders, receivers, img_e,
        be1, be2, be3, ge, bege, agg, out_edge);
    mgn_mfma<1><<<dim3((NNODES + 63) / 64), dim3(NTH), 0, stream>>>(
        nodef, edgef, senders, receivers, img_n,
        bn1, bn2, bn3, gn, begn, agg, out_node);
}

// Round 3
// 411.127 us; speedup vs baseline: 12.3305x; 1.0729x over previous
//
#include <hip/hip_runtime.h>

#define NNODES 50000
#define NEDGES 200000
#define DD 128
#define LN_EPS 1e-5f
#define NTH 256

typedef __attribute__((ext_vector_type(8))) short bf16x8;
typedef __attribute__((ext_vector_type(4))) float f32x4;

__device__ __forceinline__ unsigned short bf_rne(float f) {
    union { float f; unsigned u; } v; v.f = f;
    return (unsigned short)((v.u + 0x7fffu + ((v.u >> 16) & 1u)) >> 16);
}

// ---------------------------------------------------------------------------
// Weight image builder: W [K][128] fp32 -> bf16 image per 64-k chunk:
//   byte offset = c*16384 + n*128 + ((s*16) ^ ((n&7)<<4)), content
//   Wt[n][c*64 + s*8 + e]
// ---------------------------------------------------------------------------
__global__ void build_wimg(const float* __restrict__ We1, const float* __restrict__ We2,
                           const float* __restrict__ We3, const float* __restrict__ Wn1,
                           const float* __restrict__ Wn2, const float* __restrict__ Wn3,
                           char* __restrict__ img_e, char* __restrict__ img_n) {
    int tid = blockIdx.x * NTH + threadIdx.x;
    const float* W; char* dst; int q;
    if      (tid <  6144) { W = We1; dst = img_e;             q = tid;         }
    else if (tid <  8192) { W = We2; dst = img_e + 6 * 16384; q = tid - 6144;  }
    else if (tid < 10240) { W = We3; dst = img_e + 8 * 16384; q = tid - 8192;  }
    else if (tid < 14336) { W = Wn1; dst = img_n;             q = tid - 10240; }
    else if (tid < 16384) { W = Wn2; dst = img_n + 4 * 16384; q = tid - 14336; }
    else if (tid < 18432) { W = Wn3; dst = img_n + 6 * 16384; q = tid - 16384; }
    else return;
    int c = q >> 10, rem = q & 1023, n = rem >> 3, s = rem & 7;
    unsigned short o[8];
    #pragma unroll
    for (int e = 0; e < 8; ++e)
        o[e] = bf_rne(W[(size_t)(c * 64 + s * 8 + e) * DD + n]);
    uint4 val;
    val.x = (unsigned)o[0] | ((unsigned)o[1] << 16);
    val.y = (unsigned)o[2] | ((unsigned)o[3] << 16);
    val.z = (unsigned)o[4] | ((unsigned)o[5] << 16);
    val.w = (unsigned)o[6] | ((unsigned)o[7] << 16);
    *(uint4*)(dst + (size_t)c * 16384 + n * 128 + ((unsigned)(s * 16) ^ ((unsigned)(n & 7) << 4))) = val;
}

// ---------------------------------------------------------------------------
// CSR build: histogram -> single-block scan -> fill
// ---------------------------------------------------------------------------
__global__ void csr_histo(const int* __restrict__ recv, int* __restrict__ cnt) {
    int e = blockIdx.x * NTH + threadIdx.x;
    if (e < NEDGES) atomicAdd(&cnt[recv[e]], 1);
}

__global__ __launch_bounds__(1024)
void csr_scan(const int* __restrict__ cnt, int* __restrict__ off, int* __restrict__ cursor) {
    __shared__ int part[1024];
    const int t = threadIdx.x;
    const int CH = (NNODES + 1023) / 1024;   // 49
    const int base = t * CH;
    int s = 0;
    for (int i = 0; i < CH; ++i) {
        int idx = base + i;
        if (idx < NNODES) s += cnt[idx];
    }
    part[t] = s;
    __syncthreads();
    for (int d = 1; d < 1024; d <<= 1) {
        int v = (t >= d) ? part[t - d] : 0;
        __syncthreads();
        part[t] += v;
        __syncthreads();
    }
    int run = (t == 0) ? 0 : part[t - 1];
    for (int i = 0; i < CH; ++i) {
        int idx = base + i;
        if (idx < NNODES) {
            off[idx] = run; cursor[idx] = run;
            run += cnt[idx];
        }
    }
    if (t == 1023) off[NNODES] = NEDGES;
}

__global__ void csr_fill(const int* __restrict__ recv, int* __restrict__ cursor,
                         int* __restrict__ elist) {
    int e = blockIdx.x * NTH + threadIdx.x;
    if (e < NEDGES) {
        int p = atomicAdd(&cursor[recv[e]], 1);
        elist[p] = e;
    }
}

// ---------------------------------------------------------------------------
// Aggregate: agg[n] = sum over edges e with receiver n of (out_edge[e]-edgef[e])
// (recovers pre-residual new_edge). One wave per node, lane holds 2 cols.
// ---------------------------------------------------------------------------
__global__ __launch_bounds__(NTH)
void aggregate(const float* __restrict__ oute, const float* __restrict__ edgef,
               const int* __restrict__ off, const int* __restrict__ elist,
               float* __restrict__ agg) {
    const int n = blockIdx.x * 4 + (threadIdx.x >> 6);
    const int l = threadIdx.x & 63;
    if (n >= NNODES) return;
    const int j0 = off[n], j1 = off[n + 1];
    float sx = 0.f, sy = 0.f;
    for (int j = j0; j < j1; ++j) {
        const int e = elist[j];
        const float2 o  = ((const float2*)(oute  + (size_t)e * DD))[l];
        const float2 ef = ((const float2*)(edgef + (size_t)e * DD))[l];
        sx += o.x - ef.x;
        sy += o.y - ef.y;
    }
    float2 r; r.x = sx; r.y = sy;
    ((float2*)(agg + (size_t)n * DD))[l] = r;
}

// ---------------------------------------------------------------------------
// Fused MLP kernel.  MODE 0 = edge (K=384, gather), MODE 1 = node (K=256).
// Per block: 64 rows x 128 cols; wave w owns rows w*16..w*16+15, all cols.
// No __syncthreads: Hb rows are wave-private.
// ---------------------------------------------------------------------------
template<int MODE>
__global__ __launch_bounds__(NTH, 3)
void mgn_mfma(const float* __restrict__ nodef, const float* __restrict__ edgef,
              const int* __restrict__ senders, const int* __restrict__ receivers,
              const char* __restrict__ img,
              const float* __restrict__ b1, const float* __restrict__ b2,
              const float* __restrict__ b3,
              const float* __restrict__ gamma, const float* __restrict__ beta,
              const float* __restrict__ agg, float* __restrict__ outp)
{
    __shared__ char Hb[16384];   // H1/H2: 2 halves x [64 rows][64 k] bf16, swizzled

    const int t  = threadIdx.x;
    const int w  = t >> 6;
    const int l  = t & 63;
    const int lr = l & 15;
    const int g  = l >> 4;
    const int m_local = w * 16 + lr;
    const int row0 = blockIdx.x * 64;
    const int gm = row0 + m_local;
    constexpr int NROWS = (MODE == 0) ? NEDGES : NNODES;
    constexpr int NK1   = (MODE == 0) ? 12 : 8;
    const int gmc = gm < NROWS ? gm : NROWS - 1;
    const unsigned swz = (unsigned)(lr & 7) << 4;

    int srow = 0, rrow = 0;
    if (MODE == 0) { srow = senders[gmc]; rrow = receivers[gmc]; }

    f32x4 acc[8];
    const f32x4 fzero = {0.f, 0.f, 0.f, 0.f};
    #pragma unroll
    for (int nt = 0; nt < 8; ++nt) acc[nt] = fzero;

    auto loadA = [&](bf16x8* a, const char* imgph, int ks) {
        const char* base = imgph + (size_t)(ks >> 1) * 16384
                         + ((unsigned)((ks & 1) * 64 + g * 16) ^ swz);
        #pragma unroll
        for (int nt = 0; nt < 8; ++nt)
            a[nt] = *(const bf16x8*)(base + (nt * 16 + lr) * 128);
    };

    auto loadB1 = [&](f32x4* b, int ks) {
        const float* base;
        if (MODE == 0) {
            int seg = ks >> 2;
            base = (seg == 0) ? nodef + (size_t)srow * DD
                 : (seg == 1) ? nodef + (size_t)rrow * DD
                              : edgef + (size_t)gmc * DD;
        } else {
            base = (ks < 4) ? nodef + (size_t)gmc * DD
                            : agg   + (size_t)gmc * DD;
        }
        const float* src = base + (ks & 3) * 32 + g * 8;
        b[0] = *(const f32x4*)src;
        b[1] = *(const f32x4*)(src + 4);
    };

    auto cvtB = [&](const f32x4* braw) {
        bf16x8 r;
        #pragma unroll
        for (int i = 0; i < 4; ++i) r[i]     = (short)bf_rne(braw[0][i]);
        #pragma unroll
        for (int i = 0; i < 4; ++i) r[4 + i] = (short)bf_rne(braw[1][i]);
        return r;
    };

    auto loadBH = [&](int ks) {
        const char* p = &Hb[(ks >> 1) * 8192] + m_local * 128
                      + ((unsigned)((ks & 1) * 64 + g * 16) ^ swz);
        return *(const bf16x8*)p;
    };

    auto domfma = [&](bf16x8* a, bf16x8 b) {
        #pragma unroll
        for (int nt = 0; nt < 8; ++nt)
            acc[nt] = __builtin_amdgcn_mfma_f32_16x16x32_bf16(a[nt], b, acc[nt], 0, 0, 0);
    };

    auto epiH = [&](const float* bias) {
        #pragma unroll
        for (int nt = 0; nt < 8; ++nt) {
            f32x4 bv = *(const f32x4*)(bias + nt * 16 + g * 4);
            unsigned short h[4];
            #pragma unroll
            for (int r = 0; r < 4; ++r)
                h[r] = bf_rne(fmaxf(acc[nt][r] + bv[r], 0.f));
            char* p = &Hb[(nt >> 2) * 8192] + m_local * 128
                    + ((unsigned)(((nt & 3) * 2 + (g >> 1)) * 16) ^ swz) + (g & 1) * 8;
            unsigned lo = (unsigned)h[0] | ((unsigned)h[1] << 16);
            unsigned hi = (unsigned)h[2] | ((unsigned)h[3] << 16);
            *(unsigned long long*)p = (unsigned long long)lo | ((unsigned long long)hi << 32);
            acc[nt] = fzero;
        }
    };

    bf16x8 aA[8], aB[8];
    f32x4  bA[2], bB[2];

    // ================= phase 1: X @ W1 =================
    loadA(aA, img, 0); loadB1(bA, 0);
    #pragma unroll
    for (int ks = 0; ks < NK1; ks += 2) {
        loadA(aB, img, ks + 1); loadB1(bB, ks + 1);
        domfma(aA, cvtB(bA));
        if (ks + 2 < NK1) { loadA(aA, img, ks + 2); loadB1(bA, ks + 2); }
        domfma(aB, cvtB(bB));
    }
    epiH(b1);

    // ================= phase 2: H1 @ W2 =================
    const char* img2 = img + (size_t)((MODE == 0) ? 6 : 4) * 16384;
    loadA(aA, img2, 0);
    #pragma unroll
    for (int ks = 0; ks < 4; ks += 2) {
        loadA(aB, img2, ks + 1);
        domfma(aA, loadBH(ks));
        if (ks + 2 < 4) loadA(aA, img2, ks + 2);
        domfma(aB, loadBH(ks + 1));
    }
    epiH(b2);

    // ================= phase 3: H2 @ W3 =================
    const char* img3 = img2 + 2 * 16384;
    loadA(aA, img3, 0);
    #pragma unroll
    for (int ks = 0; ks < 4; ks += 2) {
        loadA(aB, img3, ks + 1);
        domfma(aA, loadBH(ks));
        if (ks + 2 < 4) loadA(aA, img3, ks + 2);
        domfma(aB, loadBH(ks + 1));
    }

    // ================= bias3 + LayerNorm + residual =================
    float vsum = 0.f, vsq = 0.f;
    #pragma unroll
    for (int nt = 0; nt < 8; ++nt) {
        f32x4 bv = *(const f32x4*)(b3 + nt * 16 + g * 4);
        #pragma unroll
        for (int r = 0; r < 4; ++r) {
            float v = acc[nt][r] + bv[r];
            acc[nt][r] = v;
            vsum += v; vsq += v * v;
        }
    }
    vsum += __shfl_xor(vsum, 16); vsum += __shfl_xor(vsum, 32);
    vsq  += __shfl_xor(vsq, 16);  vsq  += __shfl_xor(vsq, 32);
    const float mu = vsum * (1.f / DD);
    const float rs = rsqrtf(vsq * (1.f / DD) - mu * mu + LN_EPS);

    if (gm < NROWS) {
        const float* resid = ((MODE == 0) ? edgef : nodef) + (size_t)gm * DD;
        #pragma unroll
        for (int nt = 0; nt < 8; ++nt) {
            const int n0 = nt * 16 + g * 4;
            f32x4 gv = *(const f32x4*)(gamma + n0);
            f32x4 bv = *(const f32x4*)(beta + n0);
            f32x4 rv = *(const f32x4*)(resid + n0);
            f32x4 o;
            #pragma unroll
            for (int r = 0; r < 4; ++r)
                o[r] = (acc[nt][r] - mu) * rs * gv[r] + bv[r] + rv[r];
            *(f32x4*)(outp + (size_t)gm * DD + n0) = o;
        }
    }
}

extern "C" void kernel_launch(void* const* d_in, const int* in_sizes, int n_in,
                              void* d_out, int out_size, void* d_ws, size_t ws_size,
                              hipStream_t stream) {
    const float* nodef = (const float*)d_in[0];
    const float* edgef = (const float*)d_in[1];
    const int* senders   = (const int*)d_in[2];
    const int* receivers = (const int*)d_in[3];
    const float* We1 = (const float*)d_in[4],  *be1 = (const float*)d_in[5];
    const float* We2 = (const float*)d_in[6],  *be2 = (const float*)d_in[7];
    const float* We3 = (const float*)d_in[8],  *be3 = (const float*)d_in[9];
    const float* ge  = (const float*)d_in[10], *bege = (const float*)d_in[11];
    const float* Wn1 = (const float*)d_in[12], *bn1 = (const float*)d_in[13];
    const float* Wn2 = (const float*)d_in[14], *bn2 = (const float*)d_in[15];
    const float* Wn3 = (const float*)d_in[16], *bn3 = (const float*)d_in[17];
    const float* gn  = (const float*)d_in[18], *begn = (const float*)d_in[19];

    float* out_node = (float*)d_out;
    float* out_edge = (float*)d_out + (size_t)NNODES * DD;

    // ---- workspace layout ----
    char* ws = (char*)d_ws;
    size_t o = 0;
    float* agg  = (float*)(ws + o); o += (size_t)NNODES * DD * 4;   // 25.6 MB
    char* img_e = ws + o;           o += 10 * 16384;                 // 160 KB
    char* img_n = ws + o;           o += 8 * 16384;                  // 128 KB
    int* cnt    = (int*)(ws + o);   o += NNODES * 4;
    int* cursor = (int*)(ws + o);   o += NNODES * 4;
    int* off    = (int*)(ws + o);   o += (NNODES + 4) * 4;
    int* elist  = (int*)(ws + o);   o += NEDGES * 4;

    hipMemsetAsync(cnt, 0, NNODES * 4, stream);
    build_wimg<<<72, NTH, 0, stream>>>(We1, We2, We3, Wn1, Wn2, Wn3, img_e, img_n);

    const int egrid = (NEDGES + NTH - 1) / NTH;
    csr_histo<<<egrid, NTH, 0, stream>>>(receivers, cnt);
    csr_scan<<<1, 1024, 0, stream>>>(cnt, off, cursor);
    csr_fill<<<egrid, NTH, 0, stream>>>(receivers, cursor, elist);

    mgn_mfma<0><<<dim3((NEDGES + 63) / 64), dim3(NTH), 0, stream>>>(
        nodef, edgef, senders, receivers, img_e,
        be1, be2, be3, ge, bege, agg, out_edge);

    aggregate<<<(NNODES + 3) / 4, NTH, 0, stream>>>(out_edge, edgef, off, elist, agg);

    mgn_mfma<1><<<dim3((NNODES + 63) / 64), dim3(NTH), 0, stream>>>(
        nodef, edgef, senders, receivers, img_n,
        bn1, bn2, bn3, gn, begn, agg, out_node);
}

// Round 5
// 324.264 us; speedup vs baseline: 15.6336x; 1.2679x over previous
//
#include <hip/hip_runtime.h>

#define NNODES 50000
#define NEDGES 200000
#define DD 128
#define LN_EPS 1e-5f
#define NTH 256

typedef __attribute__((ext_vector_type(8))) short bf16x8;
typedef __attribute__((ext_vector_type(4))) float f32x4;

template<int N> struct ic { static constexpr int value = N; };

__device__ __forceinline__ unsigned short bf_rne(float f) {
    union { float f; unsigned u; } v; v.f = f;
    return (unsigned short)((v.u + 0x7fffu + ((v.u >> 16) & 1u)) >> 16);
}

__device__ __forceinline__ void gload_lds16(const void* g, void* l) {
    __builtin_amdgcn_global_load_lds(
        (const __attribute__((address_space(1))) void*)g,
        (__attribute__((address_space(3))) void*)l, 16, 0, 0);
}

// ---------------------------------------------------------------------------
// Weight image: per k32 chunk c (8 KB): for n in 0..127, g in 0..3:
//   byte = c*8192 + n*64 + S(n,g)*16,  S = ((g + (n>>2)) & 3) ^ (n & 3)
//   content: Wt[n][c*32 + g*8 + e]  e=0..7   (bf16)
// global_load_lds copies the image linearly, so LDS layout == image layout;
// compute reads with the same S formula (both-sides swizzle, rule 21).
// ---------------------------------------------------------------------------
__global__ void build_wimg(const float* __restrict__ We1, const float* __restrict__ We2,
                           const float* __restrict__ We3, const float* __restrict__ Wn1,
                           const float* __restrict__ Wn2, const float* __restrict__ Wn3,
                           char* __restrict__ img_e, char* __restrict__ img_n) {
    int tid = blockIdx.x * NTH + threadIdx.x;
    const float* W; char* dst; int q;
    if      (tid <  6144) { W = We1; dst = img_e;             q = tid;         }
    else if (tid <  8192) { W = We2; dst = img_e + 12 * 8192; q = tid - 6144;  }
    else if (tid < 10240) { W = We3; dst = img_e + 16 * 8192; q = tid - 8192;  }
    else if (tid < 14336) { W = Wn1; dst = img_n;             q = tid - 10240; }
    else if (tid < 16384) { W = Wn2; dst = img_n + 8 * 8192;  q = tid - 14336; }
    else if (tid < 18432) { W = Wn3; dst = img_n + 12 * 8192; q = tid - 16384; }
    else return;
    int c = q >> 9, rem = q & 511, n = rem >> 2, g = rem & 3;
    int S = ((g + (n >> 2)) & 3) ^ (n & 3);
    int k0 = c * 32 + g * 8;
    unsigned short o[8];
    #pragma unroll
    for (int e = 0; e < 8; ++e)
        o[e] = bf_rne(W[(size_t)(k0 + e) * DD + n]);
    uint4 val;
    val.x = (unsigned)o[0] | ((unsigned)o[1] << 16);
    val.y = (unsigned)o[2] | ((unsigned)o[3] << 16);
    val.z = (unsigned)o[4] | ((unsigned)o[5] << 16);
    val.w = (unsigned)o[6] | ((unsigned)o[7] << 16);
    *(uint4*)(dst + (size_t)c * 8192 + n * 64 + S * 16) = val;
}

// ---------------------------------------------------------------------------
// CSR build: histogram -> single-block scan -> fill
// ---------------------------------------------------------------------------
__global__ void csr_histo(const int* __restrict__ recv, int* __restrict__ cnt) {
    int e = blockIdx.x * NTH + threadIdx.x;
    if (e < NEDGES) atomicAdd(&cnt[recv[e]], 1);
}

__global__ __launch_bounds__(1024)
void csr_scan(const int* __restrict__ cnt, int* __restrict__ off, int* __restrict__ cursor) {
    __shared__ int part[1024];
    const int t = threadIdx.x;
    const int CH = (NNODES + 1023) / 1024;
    const int base = t * CH;
    int s = 0;
    for (int i = 0; i < CH; ++i) {
        int idx = base + i;
        if (idx < NNODES) s += cnt[idx];
    }
    part[t] = s;
    __syncthreads();
    for (int d = 1; d < 1024; d <<= 1) {
        int v = (t >= d) ? part[t - d] : 0;
        __syncthreads();
        part[t] += v;
        __syncthreads();
    }
    int run = (t == 0) ? 0 : part[t - 1];
    for (int i = 0; i < CH; ++i) {
        int idx = base + i;
        if (idx < NNODES) {
            off[idx] = run; cursor[idx] = run;
            run += cnt[idx];
        }
    }
    if (t == 1023) off[NNODES] = NEDGES;
}

__global__ void csr_fill(const int* __restrict__ recv, int* __restrict__ cursor,
                         int* __restrict__ elist) {
    int e = blockIdx.x * NTH + threadIdx.x;
    if (e < NEDGES) {
        int p = atomicAdd(&cursor[recv[e]], 1);
        elist[p] = e;
    }
}

// ---------------------------------------------------------------------------
// Aggregate: agg[n] = sum over receiver-edges of (out_edge[e] - edgef[e])
// ---------------------------------------------------------------------------
__global__ __launch_bounds__(NTH)
void aggregate(const float* __restrict__ oute, const float* __restrict__ edgef,
               const int* __restrict__ off, const int* __restrict__ elist,
               float* __restrict__ agg) {
    const int n = blockIdx.x * 4 + (threadIdx.x >> 6);
    const int l = threadIdx.x & 63;
    if (n >= NNODES) return;
    const int j0 = off[n], j1 = off[n + 1];
    float ax = 0.f, ay = 0.f, bx = 0.f, by = 0.f;
    int j = j0;
    for (; j + 1 < j1; j += 2) {
        const int e0 = elist[j], e1 = elist[j + 1];
        const float2 o0 = ((const float2*)(oute  + (size_t)e0 * DD))[l];
        const float2 f0 = ((const float2*)(edgef + (size_t)e0 * DD))[l];
        const float2 o1 = ((const float2*)(oute  + (size_t)e1 * DD))[l];
        const float2 f1 = ((const float2*)(edgef + (size_t)e1 * DD))[l];
        ax += o0.x - f0.x; ay += o0.y - f0.y;
        bx += o1.x - f1.x; by += o1.y - f1.y;
    }
    if (j < j1) {
        const int e = elist[j];
        const float2 o  = ((const float2*)(oute  + (size_t)e * DD))[l];
        const float2 ef = ((const float2*)(edgef + (size_t)e * DD))[l];
        ax += o.x - ef.x; ay += o.y - ef.y;
    }
    float2 r; r.x = ax + bx; r.y = ay + by;
    ((float2*)(agg + (size_t)n * DD))[l] = r;
}

// ---------------------------------------------------------------------------
// Fused MLP.  MODE 0 = edge (K=384), MODE 1 = node (K=256).
// 4 waves x 16 rows = 64 rows/block, all 128 cols per wave.
// Weights: k32 chunks (8 KB) staged via global_load_lds, 4 LDS buffers,
// staged 2 chunks ahead, counted vmcnt (never 0 mid-loop), 1 s_barrier/chunk.
// B gathers: plain f32x4 loads, 3-slot rotation, issued 2 chunks ahead
// (compiler tracks their vmcnt exactly; sched_barrier(0) fences pin order).
// H1/H2 via wave-private swizzled LDS (no barriers needed for them).
// ---------------------------------------------------------------------------
template<int MODE>
__global__ __launch_bounds__(NTH, 3)
void mgn_mfma(const float* __restrict__ nodef, const float* __restrict__ edgef,
              const int* __restrict__ senders, const int* __restrict__ receivers,
              const char* __restrict__ img,
              const float* __restrict__ b1, const float* __restrict__ b2,
              const float* __restrict__ b3,
              const float* __restrict__ gamma, const float* __restrict__ beta,
              const float* __restrict__ agg, float* __restrict__ outp)
{
    __shared__ char Wbuf[4 * 8192];   // 4 k32-chunk buffers
    __shared__ char Hb[16384];        // H1/H2, wave-private rows, swizzled

    const int t  = threadIdx.x;
    const int w  = t >> 6;
    const int l  = t & 63;
    const int lr = l & 15;
    const int g  = l >> 4;
    const int m_local = w * 16 + lr;
    const int row0 = blockIdx.x * 64;
    const int gm = row0 + m_local;
    constexpr int NROWS = (MODE == 0) ? NEDGES : NNODES;
    constexpr int NK1   = (MODE == 0) ? 12 : 8;
    constexpr int NCH   = NK1 + 8;
    const int gmc = gm < NROWS ? gm : NROWS - 1;
    const unsigned swz = (unsigned)(lr & 7) << 4;
    // per-lane A sub-offset within a chunk buffer (nt adds 1024)
    const int aoff = lr * 64 + ((((g + (lr >> 2)) & 3) ^ (lr & 3)) << 4);

    int srow = 0, rrow = 0;
    if (MODE == 0) { srow = senders[gmc]; rrow = receivers[gmc]; }

    f32x4 acc[8];
    const f32x4 fzero = {0.f, 0.f, 0.f, 0.f};
    #pragma unroll
    for (int nt = 0; nt < 8; ++nt) acc[nt] = fzero;

    f32x4 barr[3][2];

    // ---- stage weight chunk c into Wbuf[c&3] (this wave's quarter) ----
    auto stageW = [&](int c) {
        const char* src = img + (size_t)c * 8192 + w * 1024 + l * 16;
        char* dstl = Wbuf + (c & 3) * 8192 + w * 1024;
        gload_lds16(src, dstl);
        gload_lds16(src + 4096, dstl + 4096);
    };

    // ---- B gather for chunk c (plain loads; compiler-tracked vmcnt) ----
    auto loadBG = [&](int c, f32x4* dst) {
        const float* base;
        if (MODE == 0) {
            base = (c < 4) ? nodef + (size_t)srow * DD
                 : (c < 8) ? nodef + (size_t)rrow * DD
                           : edgef + (size_t)gmc * DD;
        } else {
            base = (c < 4) ? nodef + (size_t)gmc * DD
                           : agg   + (size_t)gmc * DD;
        }
        const float* p = base + (c & 3) * 32 + g * 8;
        dst[0] = *(const f32x4*)p;
        dst[1] = *(const f32x4*)(p + 4);
    };

    auto cvtB = [&](const f32x4* br) {
        bf16x8 r;
        #pragma unroll
        for (int i = 0; i < 4; ++i) r[i]     = (short)bf_rne(br[0][i]);
        #pragma unroll
        for (int i = 0; i < 4; ++i) r[4 + i] = (short)bf_rne(br[1][i]);
        return r;
    };

    auto loadBH = [&](int ks) {
        const char* p = &Hb[(ks >> 1) * 8192] + m_local * 128
                      + ((unsigned)((ks & 1) * 64 + g * 16) ^ swz);
        return *(const bf16x8*)p;
    };

    auto epiH = [&](const float* bias) {
        #pragma unroll
        for (int nt = 0; nt < 8; ++nt) {
            f32x4 bv = *(const f32x4*)(bias + nt * 16 + g * 4);
            unsigned short h[4];
            #pragma unroll
            for (int r = 0; r < 4; ++r)
                h[r] = bf_rne(fmaxf(acc[nt][r] + bv[r], 0.f));
            char* p = &Hb[(nt >> 2) * 8192] + m_local * 128
                    + ((unsigned)(((nt & 3) * 2 + (g >> 1)) * 16) ^ swz) + (g & 1) * 8;
            unsigned lo = (unsigned)h[0] | ((unsigned)h[1] << 16);
            unsigned hi = (unsigned)h[2] | ((unsigned)h[3] << 16);
            *(unsigned long long*)p = (unsigned long long)lo | ((unsigned long long)hi << 32);
            acc[nt] = fzero;
        }
    };

    // ---- compute chunk c (compile-time c via ic<>) ----
    auto compute = [&](auto cc) {
        constexpr int c = decltype(cc)::value;
        const char* bp = Wbuf + (c & 3) * 8192 + aoff;
        bf16x8 a[8];
        #pragma unroll
        for (int nt = 0; nt < 8; ++nt)
            a[nt] = *(const bf16x8*)(bp + nt * 1024);
        bf16x8 b;
        if constexpr (c < NK1) b = cvtB(barr[c % 3]);
        else                   b = loadBH((c - NK1) & 3);
        #pragma unroll
        for (int nt = 0; nt < 8; ++nt)
            acc[nt] = __builtin_amdgcn_mfma_f32_16x16x32_bf16(a[nt], b, acc[nt], 0, 0, 0);
    };

#define PITER(C, VM)                                                        \
    {                                                                       \
        if constexpr ((C) + 2 < NCH) stageW((C) + 2);                       \
        __builtin_amdgcn_sched_barrier(0);                                  \
        if constexpr ((C) + 2 < NK1) loadBG((C) + 2, barr[((C) + 2) % 3]);  \
        __builtin_amdgcn_sched_barrier(0);                                  \
        asm volatile("s_waitcnt vmcnt(" #VM ")" ::: "memory");              \
        __builtin_amdgcn_sched_barrier(0);                                  \
        __builtin_amdgcn_s_barrier();                                       \
        __builtin_amdgcn_sched_barrier(0);                                  \
        compute(ic<(C)>{});                                                 \
    }

    // prologue: chunks 0,1 staged + gathered (order pinned by fences)
    stageW(0);
    __builtin_amdgcn_sched_barrier(0);
    loadBG(0, barr[0]);
    __builtin_amdgcn_sched_barrier(0);
    stageW(1);
    __builtin_amdgcn_sched_barrier(0);
    loadBG(1, barr[1]);
    __builtin_amdgcn_sched_barrier(0);

    if constexpr (MODE == 0) {
        PITER(0, 8)  PITER(1, 8)  PITER(2, 8)  PITER(3, 8)  PITER(4, 8)
        PITER(5, 8)  PITER(6, 8)  PITER(7, 8)  PITER(8, 8)  PITER(9, 8)
        PITER(10, 6) PITER(11, 4)
        epiH(b1);
        PITER(12, 4) PITER(13, 4) PITER(14, 4) PITER(15, 4)
        epiH(b2);
        PITER(16, 4) PITER(17, 4) PITER(18, 2) PITER(19, 0)
    } else {
        PITER(0, 8)  PITER(1, 8)  PITER(2, 8)  PITER(3, 8)  PITER(4, 8)
        PITER(5, 8)  PITER(6, 6)  PITER(7, 4)
        epiH(b1);
        PITER(8, 4)  PITER(9, 4)  PITER(10, 4) PITER(11, 4)
        epiH(b2);
        PITER(12, 4) PITER(13, 4) PITER(14, 2) PITER(15, 0)
    }
#undef PITER

    // ================= bias3 + LayerNorm + residual =================
    float vsum = 0.f, vsq = 0.f;
    #pragma unroll
    for (int nt = 0; nt < 8; ++nt) {
        f32x4 bv = *(const f32x4*)(b3 + nt * 16 + g * 4);
        #pragma unroll
        for (int r = 0; r < 4; ++r) {
            float v = acc[nt][r] + bv[r];
            acc[nt][r] = v;
            vsum += v; vsq += v * v;
        }
    }
    vsum += __shfl_xor(vsum, 16); vsum += __shfl_xor(vsum, 32);
    vsq  += __shfl_xor(vsq, 16);  vsq  += __shfl_xor(vsq, 32);
    const float mu = vsum * (1.f / DD);
    const float rs = rsqrtf(vsq * (1.f / DD) - mu * mu + LN_EPS);

    if (gm < NROWS) {
        const float* resid = ((MODE == 0) ? edgef : nodef) + (size_t)gm * DD;
        #pragma unroll
        for (int nt = 0; nt < 8; ++nt) {
            const int n0 = nt * 16 + g * 4;
            f32x4 gv = *(const f32x4*)(gamma + n0);
            f32x4 bv = *(const f32x4*)(beta + n0);
            f32x4 rv = *(const f32x4*)(resid + n0);
            f32x4 o;
            #pragma unroll
            for (int r = 0; r < 4; ++r)
                o[r] = (acc[nt][r] - mu) * rs * gv[r] + bv[r] + rv[r];
            *(f32x4*)(outp + (size_t)gm * DD + n0) = o;
        }
    }
}

extern "C" void kernel_launch(void* const* d_in, const int* in_sizes, int n_in,
                              void* d_out, int out_size, void* d_ws, size_t ws_size,
                              hipStream_t stream) {
    const float* nodef = (const float*)d_in[0];
    const float* edgef = (const float*)d_in[1];
    const int* senders   = (const int*)d_in[2];
    const int* receivers = (const int*)d_in[3];
    const float* We1 = (const float*)d_in[4],  *be1 = (const float*)d_in[5];
    const float* We2 = (const float*)d_in[6],  *be2 = (const float*)d_in[7];
    const float* We3 = (const float*)d_in[8],  *be3 = (const float*)d_in[9];
    const float* ge  = (const float*)d_in[10], *bege = (const float*)d_in[11];
    const float* Wn1 = (const float*)d_in[12], *bn1 = (const float*)d_in[13];
    const float* Wn2 = (const float*)d_in[14], *bn2 = (const float*)d_in[15];
    const float* Wn3 = (const float*)d_in[16], *bn3 = (const float*)d_in[17];
    const float* gn  = (const float*)d_in[18], *begn = (const float*)d_in[19];

    float* out_node = (float*)d_out;
    float* out_edge = (float*)d_out + (size_t)NNODES * DD;

    char* ws = (char*)d_ws;
    size_t o = 0;
    float* agg  = (float*)(ws + o); o += (size_t)NNODES * DD * 4;   // 25.6 MB
    char* img_e = ws + o;           o += 20 * 8192;                  // 160 KB
    char* img_n = ws + o;           o += 16 * 8192;                  // 128 KB
    int* cnt    = (int*)(ws + o);   o += NNODES * 4;
    int* cursor = (int*)(ws + o);   o += NNODES * 4;
    int* off    = (int*)(ws + o);   o += (NNODES + 4) * 4;
    int* elist  = (int*)(ws + o);   o += NEDGES * 4;

    hipMemsetAsync(cnt, 0, NNODES * 4, stream);
    build_wimg<<<72, NTH, 0, stream>>>(We1, We2, We3, Wn1, Wn2, Wn3, img_e, img_n);

    const int egrid = (NEDGES + NTH - 1) / NTH;
    csr_histo<<<egrid, NTH, 0, stream>>>(receivers, cnt);
    csr_scan<<<1, 1024, 0, stream>>>(cnt, off, cursor);
    csr_fill<<<egrid, NTH, 0, stream>>>(receivers, cursor, elist);

    mgn_mfma<0><<<dim3((NEDGES + 63) / 64), dim3(NTH), 0, stream>>>(
        nodef, edgef, senders, receivers, img_e,
        be1, be2, be3, ge, bege, agg, out_edge);

    aggregate<<<(NNODES + 3) / 4, NTH, 0, stream>>>(out_edge, edgef, off, elist, agg);

    mgn_mfma<1><<<dim3((NNODES + 63) / 64), dim3(NTH), 0, stream>>>(
        nodef, edgef, senders, receivers, img_n,
        bn1, bn2, bn3, gn, begn, agg, out_node);
}